// Round 1
// 1042.828 us; speedup vs baseline: 1.2939x; 1.2939x over previous
//
#include <hip/hip_runtime.h>
#include <hip/hip_bf16.h>

// Round 3:
//  - proj_qkv / out_proj: bf16 MFMA GEMMs (was fp32 VALU ~900us combined).
//    Direct-global fragment loads, 128x128 block = 4 waves x (64x64), 4x4 frags.
//  - attn_mfma: removed ALL __syncthreads (P_sh is strictly per-wave; barriers
//    were forcing vmcnt(0) drain of scalar attn HBM stores 132x per block).
//    ctxt now written bf16 for direct MFMA out-proj consumption.
//  - convs read bf16 (GEMM emits bf16 pre-buffers), halving their read bytes.

constexpr int B = 2, L = 2048, D = 1024, H = 16, HD = 64;
constexpr float SCALE = 0.125f;  // 64^-0.5
constexpr int M_ROWS = B * L;    // 4096

typedef short sh8 __attribute__((ext_vector_type(8)));   // 8 x bf16 bits (4 VGPR)
typedef float f32x4 __attribute__((ext_vector_type(4))); // MFMA C/D

__device__ __forceinline__ unsigned short f2bf(float f) {
  union { float f; unsigned u; } x; x.f = f;
  unsigned r = x.u + 0x7FFFu + ((x.u >> 16) & 1u);  // RNE
  return (unsigned short)(r >> 16);
}
__device__ __forceinline__ float bf2f(unsigned short u) {
  union { unsigned u; float f; } x; x.u = ((unsigned)u) << 16;
  return x.f;
}

// ---------------- casts ----------------
__global__ __launch_bounds__(256) void cast_x_bf16(const float* __restrict__ in,
                                                   unsigned short* __restrict__ out) {
  const size_t g = (size_t)blockIdx.x * 256 + threadIdx.x;  // 8 floats each
  const float4 a = *(const float4*)&in[g * 8];
  const float4 b = *(const float4*)&in[g * 8 + 4];
  ushort4 o0, o1;
  o0.x = f2bf(a.x); o0.y = f2bf(a.y); o0.z = f2bf(a.z); o0.w = f2bf(a.w);
  o1.x = f2bf(b.x); o1.y = f2bf(b.y); o1.z = f2bf(b.z); o1.w = f2bf(b.w);
  *(ushort4*)&out[g * 8] = o0;
  *(ushort4*)&out[g * 8 + 4] = o1;
}

__global__ __launch_bounds__(256) void cast_w4_bf16(
    const float* __restrict__ wq, const float* __restrict__ wk,
    const float* __restrict__ wv, const float* __restrict__ wo,
    unsigned short* __restrict__ out) {  // 4 consecutive 1M-elem blocks
  const int z = blockIdx.z;
  const float* src = (z == 0) ? wq : (z == 1) ? wk : (z == 2) ? wv : wo;
  unsigned short* dst = out + (size_t)z * 1024 * 1024;
  const size_t g = (size_t)blockIdx.x * 256 + threadIdx.x;
  const float4 a = *(const float4*)&src[g * 8];
  const float4 b = *(const float4*)&src[g * 8 + 4];
  ushort4 o0, o1;
  o0.x = f2bf(a.x); o0.y = f2bf(a.y); o0.z = f2bf(a.z); o0.w = f2bf(a.w);
  o1.x = f2bf(b.x); o1.y = f2bf(b.y); o1.z = f2bf(b.z); o1.w = f2bf(b.w);
  *(ushort4*)&dst[g * 8] = o0;
  *(ushort4*)&dst[g * 8 + 4] = o1;
}

// ---------------- bf16 MFMA GEMM: Y[m,n] = alpha * sum_k A[m,k]*W[n,k] ----------------
// Fragment conventions proven by attn_mfma (passed harness):
//   A-operand: lane(m,kg) <- A[row0+m][k0 + kg*8 .. +8]
//   B-operand: lane(m,kg) <- W[col0+m][k0 + kg*8 .. +8]
//   C/D:       row = row0 + kg*4 + reg, col = col0 + m
template <bool BF16OUT>
__device__ __forceinline__ void gemm_mfma_body(
    const unsigned short* __restrict__ A, const unsigned short* __restrict__ W,
    void* __restrict__ Y, float alpha) {
  const int tid = threadIdx.x;
  const int wave = tid >> 6, lane = tid & 63;
  const int m = lane & 15, kg = lane >> 4;
  const int R = blockIdx.y * 128 + (wave >> 1) * 64;
  const int C = blockIdx.x * 128 + (wave & 1) * 64;

  f32x4 acc[4][4];
#pragma unroll
  for (int i = 0; i < 4; ++i)
#pragma unroll
    for (int j = 0; j < 4; ++j) acc[i][j] = (f32x4){0.f, 0.f, 0.f, 0.f};

  const unsigned short* Ab = A + (size_t)(R + m) * 1024 + kg * 8;
  const unsigned short* Wb = W + (size_t)(C + m) * 1024 + kg * 8;

  for (int k0 = 0; k0 < 1024; k0 += 32) {
    sh8 af[4], bfr[4];
#pragma unroll
    for (int i = 0; i < 4; ++i) af[i] = *(const sh8*)(Ab + (size_t)i * 16 * 1024 + k0);
#pragma unroll
    for (int j = 0; j < 4; ++j) bfr[j] = *(const sh8*)(Wb + (size_t)j * 16 * 1024 + k0);
#pragma unroll
    for (int i = 0; i < 4; ++i)
#pragma unroll
      for (int j = 0; j < 4; ++j)
        acc[i][j] = __builtin_amdgcn_mfma_f32_16x16x32_bf16(af[i], bfr[j], acc[i][j], 0, 0, 0);
  }

#pragma unroll
  for (int i = 0; i < 4; ++i)
#pragma unroll
    for (int j = 0; j < 4; ++j)
#pragma unroll
      for (int reg = 0; reg < 4; ++reg) {
        const int row = R + i * 16 + kg * 4 + reg;
        const int col = C + j * 16 + m;
        const float v = acc[i][j][reg] * alpha;
        if constexpr (BF16OUT)
          ((unsigned short*)Y)[(size_t)row * 1024 + col] = f2bf(v);
        else
          ((float*)Y)[(size_t)row * 1024 + col] = v;
      }
}

__global__ __launch_bounds__(256) void proj_mfma(
    const unsigned short* __restrict__ xb, const unsigned short* __restrict__ wb4,
    unsigned short* __restrict__ qpre, unsigned short* __restrict__ kpre,
    unsigned short* __restrict__ vpre) {
  const int z = blockIdx.z;
  const unsigned short* W = wb4 + (size_t)z * 1024 * 1024;
  unsigned short* Yo = (z == 0) ? qpre : (z == 1) ? kpre : vpre;
  gemm_mfma_body<true>(xb, W, Yo, (z == 1) ? SCALE : 1.0f);
}

__global__ __launch_bounds__(256) void outproj_mfma(
    const unsigned short* __restrict__ ctxtb, const unsigned short* __restrict__ wob,
    float* __restrict__ out) {
  gemm_mfma_body<false>(ctxtb, wob, out, 1.0f);
}

// ---------------- depthwise conv-3 (bf16 in) -> bf16 row-major (for Q, K) ----------------
__global__ __launch_bounds__(256) void dwconv_bf16(const unsigned short* __restrict__ in,
                                                   const float* __restrict__ w,
                                                   const float* __restrict__ bias,
                                                   unsigned short* __restrict__ out) {
  const int gid = blockIdx.x * 256 + threadIdx.x;  // over B*L*(D/4)
  const int d4 = gid % (D / 4);
  const int l = (gid / (D / 4)) % L;
  const int b = gid / ((D / 4) * L);
  const int d = d4 * 4;
  const size_t base = ((size_t)b * L + l) * D + d;
  const ushort4 cu = *(const ushort4*)&in[base];
  ushort4 pu = make_ushort4(0, 0, 0, 0), nu = make_ushort4(0, 0, 0, 0);
  if (l > 0) pu = *(const ushort4*)&in[base - D];
  if (l < L - 1) nu = *(const ushort4*)&in[base + D];
  float o0 = w[(d + 0) * 3 + 0] * bf2f(pu.x) + w[(d + 0) * 3 + 1] * bf2f(cu.x) + w[(d + 0) * 3 + 2] * bf2f(nu.x) + bias[d + 0];
  float o1 = w[(d + 1) * 3 + 0] * bf2f(pu.y) + w[(d + 1) * 3 + 1] * bf2f(cu.y) + w[(d + 1) * 3 + 2] * bf2f(nu.y) + bias[d + 1];
  float o2 = w[(d + 2) * 3 + 0] * bf2f(pu.z) + w[(d + 2) * 3 + 1] * bf2f(cu.z) + w[(d + 2) * 3 + 2] * bf2f(nu.z) + bias[d + 2];
  float o3 = w[(d + 3) * 3 + 0] * bf2f(pu.w) + w[(d + 3) * 3 + 1] * bf2f(cu.w) + w[(d + 3) * 3 + 2] * bf2f(nu.w) + bias[d + 3];
  ushort4 o;
  o.x = f2bf(o0); o.y = f2bf(o1); o.z = f2bf(o2); o.w = f2bf(o3);
  *(ushort4*)&out[base] = o;
}

// ------- depthwise conv-3 for V (bf16 in) -> bf16 transposed [b][h][hd][L] -------
__global__ __launch_bounds__(256) void dwconv_v_t(const unsigned short* __restrict__ in,
                                                  const float* __restrict__ w,
                                                  const float* __restrict__ bias,
                                                  unsigned short* __restrict__ vt) {
  const int l0 = blockIdx.x * 64;
  const int h = blockIdx.y, b = blockIdx.z;
  const int d0 = h * HD;
  __shared__ unsigned short T[64][72];  // [d][l], padded
  const int tid = threadIdx.x;
  const int dq = (tid & 15) * 4, lr = tid >> 4;
#pragma unroll
  for (int pass = 0; pass < 4; ++pass) {
    const int l = l0 + pass * 16 + lr;
    const size_t base = ((size_t)b * L + l) * D + d0 + dq;
    const ushort4 cu = *(const ushort4*)&in[base];
    ushort4 pu = make_ushort4(0, 0, 0, 0), nu = make_ushort4(0, 0, 0, 0);
    if (l > 0) pu = *(const ushort4*)&in[base - D];
    if (l < L - 1) nu = *(const ushort4*)&in[base + D];
    const float c[4] = {bf2f(cu.x), bf2f(cu.y), bf2f(cu.z), bf2f(cu.w)};
    const float pp[4] = {bf2f(pu.x), bf2f(pu.y), bf2f(pu.z), bf2f(pu.w)};
    const float nn[4] = {bf2f(nu.x), bf2f(nu.y), bf2f(nu.z), bf2f(nu.w)};
#pragma unroll
    for (int j = 0; j < 4; ++j) {
      const int d = d0 + dq + j;
      float o = w[d * 3 + 0] * pp[j] + w[d * 3 + 1] * c[j] + w[d * 3 + 2] * nn[j] + bias[d];
      T[dq + j][pass * 16 + lr] = f2bf(o);
    }
  }
  __syncthreads();
  const int dd = tid >> 2, lq = (tid & 3) * 16;
  const size_t rbase = ((size_t)(b * H + h) * HD + dd) * L + l0 + lq;
#pragma unroll
  for (int i = 0; i < 16; i += 4) {
    ushort4 o;
    o.x = T[dd][lq + i + 0]; o.y = T[dd][lq + i + 1];
    o.z = T[dd][lq + i + 2]; o.w = T[dd][lq + i + 3];
    *(ushort4*)&vt[rbase + i] = o;
  }
}

// ---------------- MFMA flash attention ----------------
// grid: (16 pairs, H, B); block 256 = 4 waves; wave owns 16 q-rows of each tile.
// NOTE: no __syncthreads anywhere — P_sh is strictly per-wave (each wave writes and
// reads only P_sh[wave]); within-wave ds ordering is handled by compiler waitcnts.
// This keeps the scalar attn HBM stores in flight instead of draining at barriers.
__global__ __launch_bounds__(256) void attn_mfma(
    const unsigned short* __restrict__ qb, const unsigned short* __restrict__ kb,
    const unsigned short* __restrict__ vt, float* __restrict__ attn,
    unsigned short* __restrict__ ctxtb) {
  const int p = blockIdx.x, h = blockIdx.y, b = blockIdx.z;
  const int tid = threadIdx.x;
  const int wave = tid >> 6, lane = tid & 63;
  const int m = lane & 15, kg = lane >> 4;

  __shared__ unsigned short P_sh[4][16 * 72];  // per-wave 16x64 bf16, stride 72

  const size_t bh = (size_t)b * H + h;
  const unsigned short* qbase = qb + (size_t)b * L * D + h * HD;
  const unsigned short* kbase = kb + (size_t)b * L * D + h * HD;
  const unsigned short* vbase = vt + bh * HD * L;
  float* attnb = attn + bh * L * L;

  for (int which = 0; which < 2; ++which) {
    const int qt = which ? (31 - p) : p;
    const int q0 = qt * 64;
    const int r0 = q0 + wave * 16;
    const int crow = kg * 4;  // C-layout row base for this lane (+reg)

    // Q A-fragments (rows r0+m, k = s*32 + kg*8 .. +8)
    sh8 qf[2];
#pragma unroll
    for (int s = 0; s < 2; ++s)
      qf[s] = *(const sh8*)(qbase + (size_t)(r0 + m) * D + s * 32 + kg * 8);

    // ---- pass 1: row sums l ----
    float linv[4] = {0.f, 0.f, 0.f, 0.f};
    for (int kt = 0; kt <= qt; ++kt) {
      const int kcol0 = kt * 64;
#pragma unroll
      for (int ct = 0; ct < 4; ++ct) {
        f32x4 sacc = {0.f, 0.f, 0.f, 0.f};
#pragma unroll
        for (int s = 0; s < 2; ++s) {
          sh8 kf = *(const sh8*)(kbase + (size_t)(kcol0 + ct * 16 + m) * D + s * 32 + kg * 8);
          sacc = __builtin_amdgcn_mfma_f32_16x16x32_bf16(qf[s], kf, sacc, 0, 0, 0);
        }
        const int col = kcol0 + ct * 16 + m;
#pragma unroll
        for (int reg = 0; reg < 4; ++reg) {
          const int row = r0 + crow + reg;
          linv[reg] += (col <= row) ? __expf(sacc[reg]) : 0.f;
        }
      }
    }
#pragma unroll
    for (int reg = 0; reg < 4; ++reg) {
      float v = linv[reg];
      v += __shfl_xor(v, 1); v += __shfl_xor(v, 2);
      v += __shfl_xor(v, 4); v += __shfl_xor(v, 8);
      linv[reg] = 1.0f / v;
    }

    // ---- pass 2: normalized attn write + PV ----
    f32x4 cacc[4];
#pragma unroll
    for (int ct = 0; ct < 4; ++ct) cacc[ct] = (f32x4){0.f, 0.f, 0.f, 0.f};

    for (int kt = 0; kt <= qt; ++kt) {
      const int kcol0 = kt * 64;
#pragma unroll
      for (int ct = 0; ct < 4; ++ct) {
        f32x4 sacc = {0.f, 0.f, 0.f, 0.f};
#pragma unroll
        for (int s = 0; s < 2; ++s) {
          sh8 kf = *(const sh8*)(kbase + (size_t)(kcol0 + ct * 16 + m) * D + s * 32 + kg * 8);
          sacc = __builtin_amdgcn_mfma_f32_16x16x32_bf16(qf[s], kf, sacc, 0, 0, 0);
        }
        const int col = kcol0 + ct * 16 + m;
#pragma unroll
        for (int reg = 0; reg < 4; ++reg) {
          const int row = r0 + crow + reg;
          const float pv = (col <= row) ? __expf(sacc[reg]) * linv[reg] : 0.f;
          attnb[(size_t)row * L + col] = pv;
          P_sh[wave][(crow + reg) * 72 + ct * 16 + m] = f2bf(pv);
        }
      }
      sh8 pf[2];
#pragma unroll
      for (int s = 0; s < 2; ++s)
        pf[s] = *(const sh8*)&P_sh[wave][m * 72 + s * 32 + kg * 8];
#pragma unroll
      for (int ct = 0; ct < 4; ++ct) {
#pragma unroll
        for (int s = 0; s < 2; ++s) {
          sh8 vf = *(const sh8*)(vbase + (size_t)(ct * 16 + m) * L + kcol0 + s * 32 + kg * 8);
          cacc[ct] = __builtin_amdgcn_mfma_f32_16x16x32_bf16(pf[s], vf, cacc[ct], 0, 0, 0);
        }
      }
    }

    // ctxt write (already normalized) — bf16 for MFMA out-proj
#pragma unroll
    for (int ct = 0; ct < 4; ++ct)
#pragma unroll
      for (int reg = 0; reg < 4; ++reg)
        ctxtb[(size_t)(b * L + r0 + crow + reg) * D + h * HD + ct * 16 + m] =
            f2bf(cacc[ct][reg]);

    // zero-fill strictly-upper columns for this q-tile (disjoint from pass-2 writes)
    const int zstart = q0 + 64;
    if (zstart < L) {
      const int r = tid >> 2;  // 0..63
      float* rp = attnb + (size_t)(q0 + r) * L;
      const float4 z4 = make_float4(0, 0, 0, 0);
      for (int c = zstart + (tid & 3) * 4; c < L; c += 16)
        *(float4*)&rp[c] = z4;
    }
  }
}

extern "C" void kernel_launch(void* const* d_in, const int* in_sizes, int n_in,
                              void* d_out, int out_size, void* d_ws, size_t ws_size,
                              hipStream_t stream) {
  const float* x    = (const float*)d_in[0];
  const float* wq   = (const float*)d_in[1];
  const float* wk   = (const float*)d_in[2];
  const float* wv   = (const float*)d_in[3];
  const float* wo   = (const float*)d_in[4];
  const float* cq_w = (const float*)d_in[5];
  const float* cq_b = (const float*)d_in[6];
  const float* ck_w = (const float*)d_in[7];
  const float* ck_b = (const float*)d_in[8];
  const float* cv_w = (const float*)d_in[9];
  const float* cv_b = (const float*)d_in[10];

  float* out  = (float*)d_out;                       // [B,L,D]
  float* attn = (float*)d_out + (size_t)B * L * D;   // [B,H,L,L]

  const size_t bufN = (size_t)B * L * D;  // 4,194,304 elems
  unsigned short* ws16 = (unsigned short*)d_ws;
  unsigned short* qpre  = ws16 + 0 * bufN;
  unsigned short* kpre  = ws16 + 1 * bufN;
  unsigned short* vpre  = ws16 + 2 * bufN;
  unsigned short* qb    = ws16 + 3 * bufN;
  unsigned short* kbb   = ws16 + 4 * bufN;
  unsigned short* vtb   = ws16 + 5 * bufN;
  unsigned short* ctxtb = ws16 + 6 * bufN;
  unsigned short* xb    = ws16 + 7 * bufN;
  unsigned short* wb4   = ws16 + 8 * bufN;  // 4 x 1024x1024 bf16
  // total ws use: 9 * 8 MiB = 75.5 MiB

  // 0) casts to bf16
  cast_x_bf16<<<2048, 256, 0, stream>>>(x, xb);
  cast_w4_bf16<<<dim3(512, 1, 4), 256, 0, stream>>>(wq, wk, wv, wo, wb4);
  // 1) QKV projections via MFMA (k pre-scaled by SCALE), bf16 out
  proj_mfma<<<dim3(1024 / 128, M_ROWS / 128, 3), 256, 0, stream>>>(
      xb, wb4, qpre, kpre, vpre);
  // 2) depthwise conv-3 -> bf16
  const int convBlocks = (B * L * (D / 4)) / 256;  // 4096
  dwconv_bf16<<<convBlocks, 256, 0, stream>>>(qpre, cq_w, cq_b, qb);
  dwconv_bf16<<<convBlocks, 256, 0, stream>>>(kpre, ck_w, ck_b, kbb);
  dwconv_v_t<<<dim3(L / 64, H, B), 256, 0, stream>>>(vpre, cv_w, cv_b, vtb);
  // 3) MFMA flash attention (writes attn fp32 + ctxt bf16), barrier-free
  attn_mfma<<<dim3(16, H, B), 256, 0, stream>>>(qb, kbb, vtb, attn, ctxtb);
  // 4) output projection via MFMA
  outproj_mfma<<<dim3(1024 / 128, M_ROWS / 128, 1), 256, 0, stream>>>(
      ctxtb, wb4 + 3ull * 1024 * 1024, out);
}

// Round 2
// 843.121 us; speedup vs baseline: 1.6004x; 1.2369x over previous
//
#include <hip/hip_runtime.h>
#include <hip/hip_bf16.h>

// Round 4:
//  - GEMMs: m97-style LDS-staged MFMA (128x128 tile, BK=64, global_load_lds w=16,
//    ds_read_b128 frags). Replaces direct-global frag GEMM (~57TF -> target ~500TF).
//  - Attention split:
//      flash_pv: single-pass flash (unnormalized P, scale by 1/l at end). Writes only
//        ctxt bf16 + linv. No inner-loop global stores -> no vmcnt store serialization.
//      attn_write: GEMM-shaped attn materializer, 128x128 tiles, 8192 blocks;
//        recomputes S (bit-identical), writes exp(S)*linv; upper tiles float4 zero-fill.

constexpr int B = 2, L = 2048, D = 1024, H = 16, HD = 64;
constexpr float SCALE = 0.125f;  // 64^-0.5
constexpr int M_ROWS = B * L;    // 4096

typedef short sh8 __attribute__((ext_vector_type(8)));   // 8 x bf16 bits (4 VGPR)
typedef float f32x4 __attribute__((ext_vector_type(4))); // MFMA C/D

__device__ __forceinline__ unsigned short f2bf(float f) {
  union { float f; unsigned u; } x; x.f = f;
  unsigned r = x.u + 0x7FFFu + ((x.u >> 16) & 1u);  // RNE
  return (unsigned short)(r >> 16);
}
__device__ __forceinline__ float bf2f(unsigned short u) {
  union { unsigned u; float f; } x; x.u = ((unsigned)u) << 16;
  return x.f;
}

// async global->LDS, 16B per lane; lds dest = wave-uniform base + lane*16
#define GLL16(gsrc, ldsbase)                                                  \
  __builtin_amdgcn_global_load_lds(                                           \
      (const __attribute__((address_space(1))) void*)(gsrc),                  \
      (__attribute__((address_space(3))) void*)(ldsbase), 16, 0, 0)

// ---------------- casts ----------------
__global__ __launch_bounds__(256) void cast_x_bf16(const float* __restrict__ in,
                                                   unsigned short* __restrict__ out) {
  const size_t g = (size_t)blockIdx.x * 256 + threadIdx.x;  // 8 floats each
  const float4 a = *(const float4*)&in[g * 8];
  const float4 b = *(const float4*)&in[g * 8 + 4];
  ushort4 o0, o1;
  o0.x = f2bf(a.x); o0.y = f2bf(a.y); o0.z = f2bf(a.z); o0.w = f2bf(a.w);
  o1.x = f2bf(b.x); o1.y = f2bf(b.y); o1.z = f2bf(b.z); o1.w = f2bf(b.w);
  *(ushort4*)&out[g * 8] = o0;
  *(ushort4*)&out[g * 8 + 4] = o1;
}

__global__ __launch_bounds__(256) void cast_w4_bf16(
    const float* __restrict__ wq, const float* __restrict__ wk,
    const float* __restrict__ wv, const float* __restrict__ wo,
    unsigned short* __restrict__ out) {
  const int z = blockIdx.z;
  const float* src = (z == 0) ? wq : (z == 1) ? wk : (z == 2) ? wv : wo;
  unsigned short* dst = out + (size_t)z * 1024 * 1024;
  const size_t g = (size_t)blockIdx.x * 256 + threadIdx.x;
  const float4 a = *(const float4*)&src[g * 8];
  const float4 b = *(const float4*)&src[g * 8 + 4];
  ushort4 o0, o1;
  o0.x = f2bf(a.x); o0.y = f2bf(a.y); o0.z = f2bf(a.z); o0.w = f2bf(a.w);
  o1.x = f2bf(b.x); o1.y = f2bf(b.y); o1.z = f2bf(b.z); o1.w = f2bf(b.w);
  *(ushort4*)&dst[g * 8] = o0;
  *(ushort4*)&dst[g * 8 + 4] = o1;
}

// ------------- LDS-staged bf16 MFMA GEMM: Y[m,n] = alpha * sum_k A[m,k]*W[n,k] -------------
// 128x128 block tile, BK=64, 4 waves (2x2 of 64x64). m97 structure: stage via
// global_load_lds (16B/lane), barrier, ds_read_b128 frags, 32 MFMA, barrier.
template <bool BF16OUT>
__device__ __forceinline__ void gemm_lds_body(
    const unsigned short* __restrict__ A, const unsigned short* __restrict__ W,
    void* __restrict__ Y, float alpha) {
  __shared__ __align__(16) unsigned short As[128 * 64];
  __shared__ __align__(16) unsigned short Ws[128 * 64];
  const int tid = threadIdx.x;
  const int wave = tid >> 6, lane = tid & 63;
  const int m = lane & 15, kg = lane >> 4;
  const int m0 = blockIdx.y * 128, n0 = blockIdx.x * 128;
  const int wr = wave >> 1, wc = wave & 1;
  const int srow = lane >> 3;   // 0..7: row within 8-row staging group
  const int schunk = lane & 7;  // 16B chunk (8 elems) within 64-elem row

  f32x4 acc[4][4];
#pragma unroll
  for (int i = 0; i < 4; ++i)
#pragma unroll
    for (int j = 0; j < 4; ++j) acc[i][j] = (f32x4){0.f, 0.f, 0.f, 0.f};

  for (int k0 = 0; k0 < 1024; k0 += 64) {
    // stage A-tile [128][64] and W-tile [128][64]; 4 x 1KB calls per wave per matrix
#pragma unroll
    for (int c = 0; c < 4; ++c) {
      const int grp = wave * 4 + c;        // 8-row group index (0..15)
      const int row = grp * 8 + srow;      // 0..127
      GLL16(A + (size_t)(m0 + row) * 1024 + k0 + schunk * 8,
            (char*)As + grp * 1024);
      GLL16(W + (size_t)(n0 + row) * 1024 + k0 + schunk * 8,
            (char*)Ws + grp * 1024);
    }
    __syncthreads();
    sh8 af[4][2], bfr[4][2];
#pragma unroll
    for (int i = 0; i < 4; ++i)
#pragma unroll
      for (int s = 0; s < 2; ++s) {
        af[i][s] = *(const sh8*)&As[(wr * 64 + i * 16 + m) * 64 + s * 32 + kg * 8];
        bfr[i][s] = *(const sh8*)&Ws[(wc * 64 + i * 16 + m) * 64 + s * 32 + kg * 8];
      }
#pragma unroll
    for (int s = 0; s < 2; ++s)
#pragma unroll
      for (int i = 0; i < 4; ++i)
#pragma unroll
        for (int j = 0; j < 4; ++j)
          acc[i][j] = __builtin_amdgcn_mfma_f32_16x16x32_bf16(af[i][s], bfr[j][s],
                                                             acc[i][j], 0, 0, 0);
    __syncthreads();
  }

  const int R = m0 + wr * 64, C = n0 + wc * 64;
#pragma unroll
  for (int i = 0; i < 4; ++i)
#pragma unroll
    for (int j = 0; j < 4; ++j)
#pragma unroll
      for (int reg = 0; reg < 4; ++reg) {
        const int row = R + i * 16 + kg * 4 + reg;
        const int col = C + j * 16 + m;
        const float v = acc[i][j][reg] * alpha;
        if constexpr (BF16OUT)
          ((unsigned short*)Y)[(size_t)row * 1024 + col] = f2bf(v);
        else
          ((float*)Y)[(size_t)row * 1024 + col] = v;
      }
}

__global__ __launch_bounds__(256) void proj_mfma(
    const unsigned short* __restrict__ xb, const unsigned short* __restrict__ wb4,
    unsigned short* __restrict__ qpre, unsigned short* __restrict__ kpre,
    unsigned short* __restrict__ vpre) {
  const int z = blockIdx.z;
  const unsigned short* W = wb4 + (size_t)z * 1024 * 1024;
  unsigned short* Yo = (z == 0) ? qpre : (z == 1) ? kpre : vpre;
  gemm_lds_body<true>(xb, W, Yo, (z == 1) ? SCALE : 1.0f);
}

__global__ __launch_bounds__(256) void outproj_mfma(
    const unsigned short* __restrict__ ctxtb, const unsigned short* __restrict__ wob,
    float* __restrict__ out) {
  gemm_lds_body<false>(ctxtb, wob, out, 1.0f);
}

// ---------------- depthwise conv-3 (bf16 in) -> bf16 row-major (for Q, K) ----------------
__global__ __launch_bounds__(256) void dwconv_bf16(const unsigned short* __restrict__ in,
                                                   const float* __restrict__ w,
                                                   const float* __restrict__ bias,
                                                   unsigned short* __restrict__ out) {
  const int gid = blockIdx.x * 256 + threadIdx.x;  // over B*L*(D/4)
  const int d4 = gid % (D / 4);
  const int l = (gid / (D / 4)) % L;
  const int b = gid / ((D / 4) * L);
  const int d = d4 * 4;
  const size_t base = ((size_t)b * L + l) * D + d;
  const ushort4 cu = *(const ushort4*)&in[base];
  ushort4 pu = make_ushort4(0, 0, 0, 0), nu = make_ushort4(0, 0, 0, 0);
  if (l > 0) pu = *(const ushort4*)&in[base - D];
  if (l < L - 1) nu = *(const ushort4*)&in[base + D];
  float o0 = w[(d + 0) * 3 + 0] * bf2f(pu.x) + w[(d + 0) * 3 + 1] * bf2f(cu.x) + w[(d + 0) * 3 + 2] * bf2f(nu.x) + bias[d + 0];
  float o1 = w[(d + 1) * 3 + 0] * bf2f(pu.y) + w[(d + 1) * 3 + 1] * bf2f(cu.y) + w[(d + 1) * 3 + 2] * bf2f(nu.y) + bias[d + 1];
  float o2 = w[(d + 2) * 3 + 0] * bf2f(pu.z) + w[(d + 2) * 3 + 1] * bf2f(cu.z) + w[(d + 2) * 3 + 2] * bf2f(nu.z) + bias[d + 2];
  float o3 = w[(d + 3) * 3 + 0] * bf2f(pu.w) + w[(d + 3) * 3 + 1] * bf2f(cu.w) + w[(d + 3) * 3 + 2] * bf2f(nu.w) + bias[d + 3];
  ushort4 o;
  o.x = f2bf(o0); o.y = f2bf(o1); o.z = f2bf(o2); o.w = f2bf(o3);
  *(ushort4*)&out[base] = o;
}

// ------- depthwise conv-3 for V (bf16 in) -> bf16 transposed [b][h][hd][L] -------
__global__ __launch_bounds__(256) void dwconv_v_t(const unsigned short* __restrict__ in,
                                                  const float* __restrict__ w,
                                                  const float* __restrict__ bias,
                                                  unsigned short* __restrict__ vt) {
  const int l0 = blockIdx.x * 64;
  const int h = blockIdx.y, b = blockIdx.z;
  const int d0 = h * HD;
  __shared__ unsigned short T[64][72];  // [d][l], padded
  const int tid = threadIdx.x;
  const int dq = (tid & 15) * 4, lr = tid >> 4;
#pragma unroll
  for (int pass = 0; pass < 4; ++pass) {
    const int l = l0 + pass * 16 + lr;
    const size_t base = ((size_t)b * L + l) * D + d0 + dq;
    const ushort4 cu = *(const ushort4*)&in[base];
    ushort4 pu = make_ushort4(0, 0, 0, 0), nu = make_ushort4(0, 0, 0, 0);
    if (l > 0) pu = *(const ushort4*)&in[base - D];
    if (l < L - 1) nu = *(const ushort4*)&in[base + D];
    const float c[4] = {bf2f(cu.x), bf2f(cu.y), bf2f(cu.z), bf2f(cu.w)};
    const float pp[4] = {bf2f(pu.x), bf2f(pu.y), bf2f(pu.z), bf2f(pu.w)};
    const float nn[4] = {bf2f(nu.x), bf2f(nu.y), bf2f(nu.z), bf2f(nu.w)};
#pragma unroll
    for (int j = 0; j < 4; ++j) {
      const int d = d0 + dq + j;
      float o = w[d * 3 + 0] * pp[j] + w[d * 3 + 1] * c[j] + w[d * 3 + 2] * nn[j] + bias[d];
      T[dq + j][pass * 16 + lr] = f2bf(o);
    }
  }
  __syncthreads();
  const int dd = tid >> 2, lq = (tid & 3) * 16;
  const size_t rbase = ((size_t)(b * H + h) * HD + dd) * L + l0 + lq;
#pragma unroll
  for (int i = 0; i < 16; i += 4) {
    ushort4 o;
    o.x = T[dd][lq + i + 0]; o.y = T[dd][lq + i + 1];
    o.z = T[dd][lq + i + 2]; o.w = T[dd][lq + i + 3];
    *(ushort4*)&vt[rbase + i] = o;
  }
}

// ---------------- single-pass flash (no attn stores) ----------------
// grid: (16 pairs, H, B); block 256 = 4 waves; wave owns 16 q-rows of each tile.
// Accumulates unnormalized exp(S)@V and row-sums; scales ctxt by 1/l at the end.
// Writes linv[bh][row] for the attn materializer. P_sh strictly per-wave, no barriers.
__global__ __launch_bounds__(256) void flash_pv(
    const unsigned short* __restrict__ qb, const unsigned short* __restrict__ kb,
    const unsigned short* __restrict__ vt, float* __restrict__ linv_g,
    unsigned short* __restrict__ ctxtb) {
  const int p = blockIdx.x, h = blockIdx.y, b = blockIdx.z;
  const int tid = threadIdx.x;
  const int wave = tid >> 6, lane = tid & 63;
  const int m = lane & 15, kg = lane >> 4;

  __shared__ unsigned short P_sh[4][16 * 72];

  const size_t bh = (size_t)b * H + h;
  const unsigned short* qbase = qb + (size_t)b * L * D + h * HD;
  const unsigned short* kbase = kb + (size_t)b * L * D + h * HD;
  const unsigned short* vbase = vt + bh * HD * L;
  float* lbase = linv_g + bh * L;

  for (int which = 0; which < 2; ++which) {
    const int qt = which ? (31 - p) : p;
    const int q0 = qt * 64;
    const int r0 = q0 + wave * 16;
    const int crow = kg * 4;

    sh8 qf[2];
#pragma unroll
    for (int s = 0; s < 2; ++s)
      qf[s] = *(const sh8*)(qbase + (size_t)(r0 + m) * D + s * 32 + kg * 8);

    f32x4 cacc[4];
#pragma unroll
    for (int ct = 0; ct < 4; ++ct) cacc[ct] = (f32x4){0.f, 0.f, 0.f, 0.f};
    float lsum[4] = {0.f, 0.f, 0.f, 0.f};

    for (int kt = 0; kt <= qt; ++kt) {
      const int kcol0 = kt * 64;
#pragma unroll
      for (int ct = 0; ct < 4; ++ct) {
        f32x4 sacc = {0.f, 0.f, 0.f, 0.f};
#pragma unroll
        for (int s = 0; s < 2; ++s) {
          sh8 kf = *(const sh8*)(kbase + (size_t)(kcol0 + ct * 16 + m) * D + s * 32 + kg * 8);
          sacc = __builtin_amdgcn_mfma_f32_16x16x32_bf16(qf[s], kf, sacc, 0, 0, 0);
        }
        const int col = kcol0 + ct * 16 + m;
#pragma unroll
        for (int reg = 0; reg < 4; ++reg) {
          const int row = r0 + crow + reg;
          const float e = (col <= row) ? __expf(sacc[reg]) : 0.f;
          lsum[reg] += e;
          P_sh[wave][(crow + reg) * 72 + ct * 16 + m] = f2bf(e);
        }
      }
      sh8 pf[2];
#pragma unroll
      for (int s = 0; s < 2; ++s)
        pf[s] = *(const sh8*)&P_sh[wave][m * 72 + s * 32 + kg * 8];
#pragma unroll
      for (int ct = 0; ct < 4; ++ct) {
#pragma unroll
        for (int s = 0; s < 2; ++s) {
          sh8 vf = *(const sh8*)(vbase + (size_t)(ct * 16 + m) * L + kcol0 + s * 32 + kg * 8);
          cacc[ct] = __builtin_amdgcn_mfma_f32_16x16x32_bf16(pf[s], vf, cacc[ct], 0, 0, 0);
        }
      }
    }

    float linv[4];
#pragma unroll
    for (int reg = 0; reg < 4; ++reg) {
      float v = lsum[reg];
      v += __shfl_xor(v, 1); v += __shfl_xor(v, 2);
      v += __shfl_xor(v, 4); v += __shfl_xor(v, 8);
      linv[reg] = 1.0f / v;
    }

#pragma unroll
    for (int ct = 0; ct < 4; ++ct)
#pragma unroll
      for (int reg = 0; reg < 4; ++reg)
        ctxtb[(size_t)(b * L + r0 + crow + reg) * D + h * HD + ct * 16 + m] =
            f2bf(cacc[ct][reg] * linv[reg]);

    if (m == 0) {
#pragma unroll
      for (int reg = 0; reg < 4; ++reg) lbase[r0 + crow + reg] = linv[reg];
    }
  }
}

// ---------------- attn materializer: attn[row,col] = exp(S)*linv[row] ----------------
// grid (tc=16, tr=16, bh=32); 128x128 tile; 4 waves 2x2 of 64x64. Upper tiles zero-fill.
__global__ __launch_bounds__(256) void attn_write(
    const unsigned short* __restrict__ qb, const unsigned short* __restrict__ kb,
    const float* __restrict__ linv_g, float* __restrict__ attn) {
  const int tc = blockIdx.x, tr = blockIdx.y, bhz = blockIdx.z;
  const int b = bhz >> 4, h = bhz & 15;
  float* attnb = attn + (size_t)bhz * L * L;

  if (tc > tr) {  // strictly-upper tile: zeros
    const int t = threadIdx.x;
    const int r = tr * 128 + (t >> 1);
    float* rp = attnb + (size_t)r * L + tc * 128 + (t & 1) * 64;
    const float4 z4 = make_float4(0, 0, 0, 0);
#pragma unroll
    for (int i = 0; i < 16; ++i) *(float4*)&rp[i * 4] = z4;
    return;
  }

  const int tid = threadIdx.x;
  const int wave = tid >> 6, lane = tid & 63;
  const int m = lane & 15, kg = lane >> 4;
  const int wr = wave >> 1, wc = wave & 1;
  const unsigned short* qbase = qb + (size_t)b * L * D + h * HD;
  const unsigned short* kbase = kb + (size_t)b * L * D + h * HD;
  const float* lbase = linv_g + (size_t)bhz * L;
  const int row0 = tr * 128 + wr * 64, col0 = tc * 128 + wc * 64;

  sh8 qf[4][2];
#pragma unroll
  for (int i = 0; i < 4; ++i)
#pragma unroll
    for (int s = 0; s < 2; ++s)
      qf[i][s] = *(const sh8*)(qbase + (size_t)(row0 + i * 16 + m) * D + s * 32 + kg * 8);

  f32x4 acc[4][4];
#pragma unroll
  for (int i = 0; i < 4; ++i)
#pragma unroll
    for (int j = 0; j < 4; ++j) acc[i][j] = (f32x4){0.f, 0.f, 0.f, 0.f};

#pragma unroll
  for (int s = 0; s < 2; ++s)
#pragma unroll
    for (int j = 0; j < 4; ++j) {
      sh8 kf = *(const sh8*)(kbase + (size_t)(col0 + j * 16 + m) * D + s * 32 + kg * 8);
#pragma unroll
      for (int i = 0; i < 4; ++i)
        acc[i][j] = __builtin_amdgcn_mfma_f32_16x16x32_bf16(qf[i][s], kf, acc[i][j], 0, 0, 0);
    }

  const bool diag = (tc == tr);
#pragma unroll
  for (int i = 0; i < 4; ++i)
#pragma unroll
    for (int reg = 0; reg < 4; ++reg) {
      const int row = row0 + i * 16 + kg * 4 + reg;
      const float li = lbase[row];
      float* rowp = attnb + (size_t)row * L;
#pragma unroll
      for (int j = 0; j < 4; ++j) {
        const int col = col0 + j * 16 + m;
        float val = __expf(acc[i][j][reg]) * li;
        if (diag && col > row) val = 0.f;
        rowp[col] = val;
      }
    }
}

extern "C" void kernel_launch(void* const* d_in, const int* in_sizes, int n_in,
                              void* d_out, int out_size, void* d_ws, size_t ws_size,
                              hipStream_t stream) {
  const float* x    = (const float*)d_in[0];
  const float* wq   = (const float*)d_in[1];
  const float* wk   = (const float*)d_in[2];
  const float* wv   = (const float*)d_in[3];
  const float* wo   = (const float*)d_in[4];
  const float* cq_w = (const float*)d_in[5];
  const float* cq_b = (const float*)d_in[6];
  const float* ck_w = (const float*)d_in[7];
  const float* ck_b = (const float*)d_in[8];
  const float* cv_w = (const float*)d_in[9];
  const float* cv_b = (const float*)d_in[10];

  float* out  = (float*)d_out;                       // [B,L,D]
  float* attn = (float*)d_out + (size_t)B * L * D;   // [B,H,L,L]

  const size_t bufN = (size_t)B * L * D;  // 4,194,304 elems
  unsigned short* ws16 = (unsigned short*)d_ws;
  unsigned short* qpre  = ws16 + 0 * bufN;
  unsigned short* kpre  = ws16 + 1 * bufN;
  unsigned short* vpre  = ws16 + 2 * bufN;
  unsigned short* qb    = ws16 + 3 * bufN;
  unsigned short* kbb   = ws16 + 4 * bufN;
  unsigned short* vtb   = ws16 + 5 * bufN;
  unsigned short* ctxtb = ws16 + 6 * bufN;
  unsigned short* xb    = ws16 + 7 * bufN;
  unsigned short* wb4   = ws16 + 8 * bufN;            // 4 x 1024x1024 bf16
  float* linv_g = (float*)(ws16 + 9 * bufN);          // [B*H][L] = 256 KiB
  // total ws use: 75.75 MiB

  // 0) casts to bf16
  cast_x_bf16<<<2048, 256, 0, stream>>>(x, xb);
  cast_w4_bf16<<<dim3(512, 1, 4), 256, 0, stream>>>(wq, wk, wv, wo, wb4);
  // 1) QKV projections via LDS-staged MFMA (k pre-scaled by SCALE), bf16 out
  proj_mfma<<<dim3(1024 / 128, M_ROWS / 128, 3), 256, 0, stream>>>(
      xb, wb4, qpre, kpre, vpre);
  // 2) depthwise conv-3 -> bf16
  const int convBlocks = (B * L * (D / 4)) / 256;  // 4096
  dwconv_bf16<<<convBlocks, 256, 0, stream>>>(qpre, cq_w, cq_b, qb);
  dwconv_bf16<<<convBlocks, 256, 0, stream>>>(kpre, ck_w, ck_b, kbb);
  dwconv_v_t<<<dim3(L / 64, H, B), 256, 0, stream>>>(vpre, cv_w, cv_b, vtb);
  // 3) single-pass flash: ctxt bf16 + linv
  flash_pv<<<dim3(16, H, B), 256, 0, stream>>>(qb, kbb, vtb, linv_g, ctxtb);
  // 4) attn materializer (write-bound)
  attn_write<<<dim3(16, 16, B * H), 256, 0, stream>>>(qb, kbb, linv_g, attn);
  // 5) output projection via LDS-staged MFMA
  outproj_mfma<<<dim3(1024 / 128, M_ROWS / 128, 1), 256, 0, stream>>>(
      ctxtb, wb4 + 3ull * 1024 * 1024, out);
}

// Round 3
// 833.691 us; speedup vs baseline: 1.6185x; 1.0113x over previous
//
#include <hip/hip_runtime.h>
#include <hip/hip_bf16.h>

// Round 5:
//  - GEMMs: fixed 16-way LDS bank conflict on fragment ds_read_b128 (row stride
//    128B). XOR-swizzle chunk index: pre-swizzled global_load_lds SOURCE +
//    same XOR on the ds_read (rule: both-sides-or-neither, LDS dest stays linear).
//  - flash_pv: in-block split-K over kt parity. 512 threads = 8 waves; waves 0-3
//    even kt, 4-7 odd kt, same 64-row q-tile pair; combine cacc/lsum via padded
//    LDS (stride 68, conflict-free), 2 barriers per q-tile. 8 -> 16 waves/CU.
//  - attn_write unchanged (write-bound materializer).

constexpr int B = 2, L = 2048, D = 1024, H = 16, HD = 64;
constexpr float SCALE = 0.125f;  // 64^-0.5
constexpr int M_ROWS = B * L;    // 4096

typedef short sh8 __attribute__((ext_vector_type(8)));   // 8 x bf16 bits (4 VGPR)
typedef float f32x4 __attribute__((ext_vector_type(4))); // MFMA C/D

__device__ __forceinline__ unsigned short f2bf(float f) {
  union { float f; unsigned u; } x; x.f = f;
  unsigned r = x.u + 0x7FFFu + ((x.u >> 16) & 1u);  // RNE
  return (unsigned short)(r >> 16);
}
__device__ __forceinline__ float bf2f(unsigned short u) {
  union { unsigned u; float f; } x; x.u = ((unsigned)u) << 16;
  return x.f;
}

// async global->LDS, 16B per lane; lds dest = wave-uniform base + lane*16
#define GLL16(gsrc, ldsbase)                                                  \
  __builtin_amdgcn_global_load_lds(                                           \
      (const __attribute__((address_space(1))) void*)(gsrc),                  \
      (__attribute__((address_space(3))) void*)(ldsbase), 16, 0, 0)

// ---------------- casts ----------------
__global__ __launch_bounds__(256) void cast_x_bf16(const float* __restrict__ in,
                                                   unsigned short* __restrict__ out) {
  const size_t g = (size_t)blockIdx.x * 256 + threadIdx.x;  // 8 floats each
  const float4 a = *(const float4*)&in[g * 8];
  const float4 b = *(const float4*)&in[g * 8 + 4];
  ushort4 o0, o1;
  o0.x = f2bf(a.x); o0.y = f2bf(a.y); o0.z = f2bf(a.z); o0.w = f2bf(a.w);
  o1.x = f2bf(b.x); o1.y = f2bf(b.y); o1.z = f2bf(b.z); o1.w = f2bf(b.w);
  *(ushort4*)&out[g * 8] = o0;
  *(ushort4*)&out[g * 8 + 4] = o1;
}

__global__ __launch_bounds__(256) void cast_w4_bf16(
    const float* __restrict__ wq, const float* __restrict__ wk,
    const float* __restrict__ wv, const float* __restrict__ wo,
    unsigned short* __restrict__ out) {
  const int z = blockIdx.z;
  const float* src = (z == 0) ? wq : (z == 1) ? wk : (z == 2) ? wv : wo;
  unsigned short* dst = out + (size_t)z * 1024 * 1024;
  const size_t g = (size_t)blockIdx.x * 256 + threadIdx.x;
  const float4 a = *(const float4*)&src[g * 8];
  const float4 b = *(const float4*)&src[g * 8 + 4];
  ushort4 o0, o1;
  o0.x = f2bf(a.x); o0.y = f2bf(a.y); o0.z = f2bf(a.z); o0.w = f2bf(a.w);
  o1.x = f2bf(b.x); o1.y = f2bf(b.y); o1.z = f2bf(b.z); o1.w = f2bf(b.w);
  *(ushort4*)&dst[g * 8] = o0;
  *(ushort4*)&dst[g * 8 + 4] = o1;
}

// ------------- LDS-staged bf16 MFMA GEMM: Y[m,n] = alpha * sum_k A[m,k]*W[n,k] -------------
// 128x128 block tile, BK=64, 4 waves (2x2 of 64x64).
// LDS tile [128][64] bf16, linear dest for global_load_lds; bank-conflict fix:
// 16B-chunk index XOR'd with (row&7) on BOTH the global source and the ds_read.
template <bool BF16OUT>
__device__ __forceinline__ void gemm_lds_body(
    const unsigned short* __restrict__ A, const unsigned short* __restrict__ W,
    void* __restrict__ Y, float alpha) {
  __shared__ __align__(16) unsigned short As[128 * 64];
  __shared__ __align__(16) unsigned short Ws[128 * 64];
  const int tid = threadIdx.x;
  const int wave = tid >> 6, lane = tid & 63;
  const int m = lane & 15, kg = lane >> 4;
  const int m0 = blockIdx.y * 128, n0 = blockIdx.x * 128;
  const int wr = wave >> 1, wc = wave & 1;
  const int srow = lane >> 3;   // 0..7: row within 8-row staging group
  const int schunk = lane & 7;  // 16B chunk (8 elems) within 64-elem row

  f32x4 acc[4][4];
#pragma unroll
  for (int i = 0; i < 4; ++i)
#pragma unroll
    for (int j = 0; j < 4; ++j) acc[i][j] = (f32x4){0.f, 0.f, 0.f, 0.f};

  // pre-swizzled source chunk: LDS position chunk c holds global chunk c^(row&7)
  const int sch = (schunk ^ srow) * 8;  // element offset within 64-elem row

  for (int k0 = 0; k0 < 1024; k0 += 64) {
#pragma unroll
    for (int c = 0; c < 4; ++c) {
      const int grp = wave * 4 + c;        // 8-row group index (0..15)
      const int row = grp * 8 + srow;      // 0..127
      GLL16(A + (size_t)(m0 + row) * 1024 + k0 + sch, (char*)As + grp * 1024);
      GLL16(W + (size_t)(n0 + row) * 1024 + k0 + sch, (char*)Ws + grp * 1024);
    }
    __syncthreads();
    sh8 af[4][2], bfr[4][2];
#pragma unroll
    for (int i = 0; i < 4; ++i) {
      const int ra = wr * 64 + i * 16 + m;
      const int rb = wc * 64 + i * 16 + m;
      const int x7 = m & 7;  // == row&7 for both ra, rb
#pragma unroll
      for (int s = 0; s < 2; ++s) {
        const int ch = ((s * 4 + kg) ^ x7) * 8;  // de-swizzled chunk
        af[i][s]  = *(const sh8*)&As[ra * 64 + ch];
        bfr[i][s] = *(const sh8*)&Ws[rb * 64 + ch];
      }
    }
#pragma unroll
    for (int s = 0; s < 2; ++s)
#pragma unroll
      for (int i = 0; i < 4; ++i)
#pragma unroll
        for (int j = 0; j < 4; ++j)
          acc[i][j] = __builtin_amdgcn_mfma_f32_16x16x32_bf16(af[i][s], bfr[j][s],
                                                             acc[i][j], 0, 0, 0);
    __syncthreads();
  }

  const int R = m0 + wr * 64, C = n0 + wc * 64;
#pragma unroll
  for (int i = 0; i < 4; ++i)
#pragma unroll
    for (int j = 0; j < 4; ++j)
#pragma unroll
      for (int reg = 0; reg < 4; ++reg) {
        const int row = R + i * 16 + kg * 4 + reg;
        const int col = C + j * 16 + m;
        const float v = acc[i][j][reg] * alpha;
        if constexpr (BF16OUT)
          ((unsigned short*)Y)[(size_t)row * 1024 + col] = f2bf(v);
        else
          ((float*)Y)[(size_t)row * 1024 + col] = v;
      }
}

__global__ __launch_bounds__(256) void proj_mfma(
    const unsigned short* __restrict__ xb, const unsigned short* __restrict__ wb4,
    unsigned short* __restrict__ qpre, unsigned short* __restrict__ kpre,
    unsigned short* __restrict__ vpre) {
  const int z = blockIdx.z;
  const unsigned short* W = wb4 + (size_t)z * 1024 * 1024;
  unsigned short* Yo = (z == 0) ? qpre : (z == 1) ? kpre : vpre;
  gemm_lds_body<true>(xb, W, Yo, (z == 1) ? SCALE : 1.0f);
}

__global__ __launch_bounds__(256) void outproj_mfma(
    const unsigned short* __restrict__ ctxtb, const unsigned short* __restrict__ wob,
    float* __restrict__ out) {
  gemm_lds_body<false>(ctxtb, wob, out, 1.0f);
}

// ---------------- depthwise conv-3 (bf16 in) -> bf16 row-major (for Q, K) ----------------
__global__ __launch_bounds__(256) void dwconv_bf16(const unsigned short* __restrict__ in,
                                                   const float* __restrict__ w,
                                                   const float* __restrict__ bias,
                                                   unsigned short* __restrict__ out) {
  const int gid = blockIdx.x * 256 + threadIdx.x;  // over B*L*(D/4)
  const int d4 = gid % (D / 4);
  const int l = (gid / (D / 4)) % L;
  const int b = gid / ((D / 4) * L);
  const int d = d4 * 4;
  const size_t base = ((size_t)b * L + l) * D + d;
  const ushort4 cu = *(const ushort4*)&in[base];
  ushort4 pu = make_ushort4(0, 0, 0, 0), nu = make_ushort4(0, 0, 0, 0);
  if (l > 0) pu = *(const ushort4*)&in[base - D];
  if (l < L - 1) nu = *(const ushort4*)&in[base + D];
  float o0 = w[(d + 0) * 3 + 0] * bf2f(pu.x) + w[(d + 0) * 3 + 1] * bf2f(cu.x) + w[(d + 0) * 3 + 2] * bf2f(nu.x) + bias[d + 0];
  float o1 = w[(d + 1) * 3 + 0] * bf2f(pu.y) + w[(d + 1) * 3 + 1] * bf2f(cu.y) + w[(d + 1) * 3 + 2] * bf2f(nu.y) + bias[d + 1];
  float o2 = w[(d + 2) * 3 + 0] * bf2f(pu.z) + w[(d + 2) * 3 + 1] * bf2f(cu.z) + w[(d + 2) * 3 + 2] * bf2f(nu.z) + bias[d + 2];
  float o3 = w[(d + 3) * 3 + 0] * bf2f(pu.w) + w[(d + 3) * 3 + 1] * bf2f(cu.w) + w[(d + 3) * 3 + 2] * bf2f(nu.w) + bias[d + 3];
  ushort4 o;
  o.x = f2bf(o0); o.y = f2bf(o1); o.z = f2bf(o2); o.w = f2bf(o3);
  *(ushort4*)&out[base] = o;
}

// ------- depthwise conv-3 for V (bf16 in) -> bf16 transposed [b][h][hd][L] -------
__global__ __launch_bounds__(256) void dwconv_v_t(const unsigned short* __restrict__ in,
                                                  const float* __restrict__ w,
                                                  const float* __restrict__ bias,
                                                  unsigned short* __restrict__ vt) {
  const int l0 = blockIdx.x * 64;
  const int h = blockIdx.y, b = blockIdx.z;
  const int d0 = h * HD;
  __shared__ unsigned short T[64][72];  // [d][l], padded
  const int tid = threadIdx.x;
  const int dq = (tid & 15) * 4, lr = tid >> 4;
#pragma unroll
  for (int pass = 0; pass < 4; ++pass) {
    const int l = l0 + pass * 16 + lr;
    const size_t base = ((size_t)b * L + l) * D + d0 + dq;
    const ushort4 cu = *(const ushort4*)&in[base];
    ushort4 pu = make_ushort4(0, 0, 0, 0), nu = make_ushort4(0, 0, 0, 0);
    if (l > 0) pu = *(const ushort4*)&in[base - D];
    if (l < L - 1) nu = *(const ushort4*)&in[base + D];
    const float c[4] = {bf2f(cu.x), bf2f(cu.y), bf2f(cu.z), bf2f(cu.w)};
    const float pp[4] = {bf2f(pu.x), bf2f(pu.y), bf2f(pu.z), bf2f(pu.w)};
    const float nn[4] = {bf2f(nu.x), bf2f(nu.y), bf2f(nu.z), bf2f(nu.w)};
#pragma unroll
    for (int j = 0; j < 4; ++j) {
      const int d = d0 + dq + j;
      float o = w[d * 3 + 0] * pp[j] + w[d * 3 + 1] * c[j] + w[d * 3 + 2] * nn[j] + bias[d];
      T[dq + j][pass * 16 + lr] = f2bf(o);
    }
  }
  __syncthreads();
  const int dd = tid >> 2, lq = (tid & 3) * 16;
  const size_t rbase = ((size_t)(b * H + h) * HD + dd) * L + l0 + lq;
#pragma unroll
  for (int i = 0; i < 16; i += 4) {
    ushort4 o;
    o.x = T[dd][lq + i + 0]; o.y = T[dd][lq + i + 1];
    o.z = T[dd][lq + i + 2]; o.w = T[dd][lq + i + 3];
    *(ushort4*)&vt[rbase + i] = o;
  }
}

// ---------------- single-pass flash, split-K over kt parity ----------------
// grid: (16 pairs, H, B); block 512 = 8 waves. Wave wg=wave&3 owns 16 q-rows;
// half=wave>>2 processes kt = half, half+2, ... Partial cacc/lsum combined via
// LDS (padded stride 68, conflict-free). 2 barriers per q-tile.
__global__ __launch_bounds__(512) void flash_pv(
    const unsigned short* __restrict__ qb, const unsigned short* __restrict__ kb,
    const unsigned short* __restrict__ vt, float* __restrict__ linv_g,
    unsigned short* __restrict__ ctxtb) {
  const int p = blockIdx.x, h = blockIdx.y, b = blockIdx.z;
  const int tid = threadIdx.x;
  const int wave = tid >> 6, lane = tid & 63;
  const int wg = wave & 3, half = wave >> 2;
  const int m = lane & 15, kg = lane >> 4;

  __shared__ unsigned short P_sh[8][16 * 72];  // per-wave P tile
  __shared__ float cpart[64 * 68];             // half-1 cacc staging (padded)
  __shared__ float lpart[64];                  // half-1 row sums

  const size_t bh = (size_t)b * H + h;
  const unsigned short* qbase = qb + (size_t)b * L * D + h * HD;
  const unsigned short* kbase = kb + (size_t)b * L * D + h * HD;
  const unsigned short* vbase = vt + bh * HD * L;
  float* lbase = linv_g + bh * L;

  for (int which = 0; which < 2; ++which) {
    const int qt = which ? (31 - p) : p;
    const int q0 = qt * 64;
    const int r0 = q0 + wg * 16;
    const int crow = kg * 4;

    sh8 qf[2];
#pragma unroll
    for (int s = 0; s < 2; ++s)
      qf[s] = *(const sh8*)(qbase + (size_t)(r0 + m) * D + s * 32 + kg * 8);

    f32x4 cacc[4];
#pragma unroll
    for (int ct = 0; ct < 4; ++ct) cacc[ct] = (f32x4){0.f, 0.f, 0.f, 0.f};
    float lsum[4] = {0.f, 0.f, 0.f, 0.f};

    for (int kt = half; kt <= qt; kt += 2) {
      const int kcol0 = kt * 64;
#pragma unroll
      for (int ct = 0; ct < 4; ++ct) {
        f32x4 sacc = {0.f, 0.f, 0.f, 0.f};
#pragma unroll
        for (int s = 0; s < 2; ++s) {
          sh8 kf = *(const sh8*)(kbase + (size_t)(kcol0 + ct * 16 + m) * D + s * 32 + kg * 8);
          sacc = __builtin_amdgcn_mfma_f32_16x16x32_bf16(qf[s], kf, sacc, 0, 0, 0);
        }
        const int col = kcol0 + ct * 16 + m;
#pragma unroll
        for (int reg = 0; reg < 4; ++reg) {
          const int row = r0 + crow + reg;
          const float e = (col <= row) ? __expf(sacc[reg]) : 0.f;
          lsum[reg] += e;
          P_sh[wave][(crow + reg) * 72 + ct * 16 + m] = f2bf(e);
        }
      }
      sh8 pf[2];
#pragma unroll
      for (int s = 0; s < 2; ++s)
        pf[s] = *(const sh8*)&P_sh[wave][m * 72 + s * 32 + kg * 8];
#pragma unroll
      for (int ct = 0; ct < 4; ++ct) {
#pragma unroll
        for (int s = 0; s < 2; ++s) {
          sh8 vf = *(const sh8*)(vbase + (size_t)(ct * 16 + m) * L + kcol0 + s * 32 + kg * 8);
          cacc[ct] = __builtin_amdgcn_mfma_f32_16x16x32_bf16(pf[s], vf, cacc[ct], 0, 0, 0);
        }
      }
    }

    // reduce lsum across the 16 m-lanes (full row sum for this half)
#pragma unroll
    for (int reg = 0; reg < 4; ++reg) {
      float v = lsum[reg];
      v += __shfl_xor(v, 1); v += __shfl_xor(v, 2);
      v += __shfl_xor(v, 4); v += __shfl_xor(v, 8);
      lsum[reg] = v;
    }

    if (half == 1) {
      if (m == 0) {
#pragma unroll
        for (int reg = 0; reg < 4; ++reg) lpart[wg * 16 + crow + reg] = lsum[reg];
      }
#pragma unroll
      for (int ct = 0; ct < 4; ++ct)
#pragma unroll
        for (int reg = 0; reg < 4; ++reg)
          cpart[(wg * 16 + crow + reg) * 68 + ct * 16 + m] = cacc[ct][reg];
    }
    __syncthreads();
    if (half == 0) {
      float linv[4];
#pragma unroll
      for (int reg = 0; reg < 4; ++reg)
        linv[reg] = 1.0f / (lsum[reg] + lpart[wg * 16 + crow + reg]);
#pragma unroll
      for (int ct = 0; ct < 4; ++ct)
#pragma unroll
        for (int reg = 0; reg < 4; ++reg) {
          const float v = cacc[ct][reg] + cpart[(wg * 16 + crow + reg) * 68 + ct * 16 + m];
          ctxtb[(size_t)(b * L + r0 + crow + reg) * D + h * HD + ct * 16 + m] =
              f2bf(v * linv[reg]);
        }
      if (m == 0) {
#pragma unroll
        for (int reg = 0; reg < 4; ++reg) lbase[r0 + crow + reg] = linv[reg];
      }
    }
    __syncthreads();
  }
}

// ---------------- attn materializer: attn[row,col] = exp(S)*linv[row] ----------------
// grid (tc=16, tr=16, bh=32); 128x128 tile; 4 waves 2x2 of 64x64. Upper tiles zero-fill.
__global__ __launch_bounds__(256) void attn_write(
    const unsigned short* __restrict__ qb, const unsigned short* __restrict__ kb,
    const float* __restrict__ linv_g, float* __restrict__ attn) {
  const int tc = blockIdx.x, tr = blockIdx.y, bhz = blockIdx.z;
  const int b = bhz >> 4, h = bhz & 15;
  float* attnb = attn + (size_t)bhz * L * L;

  if (tc > tr) {  // strictly-upper tile: zeros
    const int t = threadIdx.x;
    const int r = tr * 128 + (t >> 1);
    float* rp = attnb + (size_t)r * L + tc * 128 + (t & 1) * 64;
    const float4 z4 = make_float4(0, 0, 0, 0);
#pragma unroll
    for (int i = 0; i < 16; ++i) *(float4*)&rp[i * 4] = z4;
    return;
  }

  const int tid = threadIdx.x;
  const int wave = tid >> 6, lane = tid & 63;
  const int m = lane & 15, kg = lane >> 4;
  const int wr = wave >> 1, wc = wave & 1;
  const unsigned short* qbase = qb + (size_t)b * L * D + h * HD;
  const unsigned short* kbase = kb + (size_t)b * L * D + h * HD;
  const float* lbase = linv_g + (size_t)bhz * L;
  const int row0 = tr * 128 + wr * 64, col0 = tc * 128 + wc * 64;

  sh8 qf[4][2];
#pragma unroll
  for (int i = 0; i < 4; ++i)
#pragma unroll
    for (int s = 0; s < 2; ++s)
      qf[i][s] = *(const sh8*)(qbase + (size_t)(row0 + i * 16 + m) * D + s * 32 + kg * 8);

  f32x4 acc[4][4];
#pragma unroll
  for (int i = 0; i < 4; ++i)
#pragma unroll
    for (int j = 0; j < 4; ++j) acc[i][j] = (f32x4){0.f, 0.f, 0.f, 0.f};

#pragma unroll
  for (int s = 0; s < 2; ++s)
#pragma unroll
    for (int j = 0; j < 4; ++j) {
      sh8 kf = *(const sh8*)(kbase + (size_t)(col0 + j * 16 + m) * D + s * 32 + kg * 8);
#pragma unroll
      for (int i = 0; i < 4; ++i)
        acc[i][j] = __builtin_amdgcn_mfma_f32_16x16x32_bf16(qf[i][s], kf, acc[i][j], 0, 0, 0);
    }

  const bool diag = (tc == tr);
#pragma unroll
  for (int i = 0; i < 4; ++i)
#pragma unroll
    for (int reg = 0; reg < 4; ++reg) {
      const int row = row0 + i * 16 + kg * 4 + reg;
      const float li = lbase[row];
      float* rowp = attnb + (size_t)row * L;
#pragma unroll
      for (int j = 0; j < 4; ++j) {
        const int col = col0 + j * 16 + m;
        float val = __expf(acc[i][j][reg]) * li;
        if (diag && col > row) val = 0.f;
        rowp[col] = val;
      }
    }
}

extern "C" void kernel_launch(void* const* d_in, const int* in_sizes, int n_in,
                              void* d_out, int out_size, void* d_ws, size_t ws_size,
                              hipStream_t stream) {
  const float* x    = (const float*)d_in[0];
  const float* wq   = (const float*)d_in[1];
  const float* wk   = (const float*)d_in[2];
  const float* wv   = (const float*)d_in[3];
  const float* wo   = (const float*)d_in[4];
  const float* cq_w = (const float*)d_in[5];
  const float* cq_b = (const float*)d_in[6];
  const float* ck_w = (const float*)d_in[7];
  const float* ck_b = (const float*)d_in[8];
  const float* cv_w = (const float*)d_in[9];
  const float* cv_b = (const float*)d_in[10];

  float* out  = (float*)d_out;                       // [B,L,D]
  float* attn = (float*)d_out + (size_t)B * L * D;   // [B,H,L,L]

  const size_t bufN = (size_t)B * L * D;  // 4,194,304 elems
  unsigned short* ws16 = (unsigned short*)d_ws;
  unsigned short* qpre  = ws16 + 0 * bufN;
  unsigned short* kpre  = ws16 + 1 * bufN;
  unsigned short* vpre  = ws16 + 2 * bufN;
  unsigned short* qb    = ws16 + 3 * bufN;
  unsigned short* kbb   = ws16 + 4 * bufN;
  unsigned short* vtb   = ws16 + 5 * bufN;
  unsigned short* ctxtb = ws16 + 6 * bufN;
  unsigned short* xb    = ws16 + 7 * bufN;
  unsigned short* wb4   = ws16 + 8 * bufN;            // 4 x 1024x1024 bf16
  float* linv_g = (float*)(ws16 + 9 * bufN);          // [B*H][L] = 256 KiB
  // total ws use: 75.75 MiB

  // 0) casts to bf16
  cast_x_bf16<<<2048, 256, 0, stream>>>(x, xb);
  cast_w4_bf16<<<dim3(512, 1, 4), 256, 0, stream>>>(wq, wk, wv, wo, wb4);
  // 1) QKV projections via LDS-staged MFMA (k pre-scaled by SCALE), bf16 out
  proj_mfma<<<dim3(1024 / 128, M_ROWS / 128, 3), 256, 0, stream>>>(
      xb, wb4, qpre, kpre, vpre);
  // 2) depthwise conv-3 -> bf16
  const int convBlocks = (B * L * (D / 4)) / 256;  // 4096
  dwconv_bf16<<<convBlocks, 256, 0, stream>>>(qpre, cq_w, cq_b, qb);
  dwconv_bf16<<<convBlocks, 256, 0, stream>>>(kpre, ck_w, ck_b, kbb);
  dwconv_v_t<<<dim3(L / 64, H, B), 256, 0, stream>>>(vpre, cv_w, cv_b, vtb);
  // 3) single-pass flash (split-K): ctxt bf16 + linv
  flash_pv<<<dim3(16, H, B), 512, 0, stream>>>(qb, kbb, vtb, linv_g, ctxtb);
  // 4) attn materializer (write-bound)
  attn_write<<<dim3(16, 16, B * H), 256, 0, stream>>>(qb, kbb, linv_g, attn);
  // 5) output projection via LDS-staged MFMA
  outproj_mfma<<<dim3(1024 / 128, M_ROWS / 128, 1), 256, 0, stream>>>(
      ctxtb, wb4 + 3ull * 1024 * 1024, out);
}